// Round 4
// baseline (435.983 us; speedup 1.0000x reference)
//
#include <hip/hip_runtime.h>
#include <hip/hip_bf16.h>

// GapModel: per_row[n] = (1/||ps_n||^2) * sum_m w[s_n,m] * (ps_n . sp[s_n,m])^2
// energy[t] = sum_{n: sid[n]==t} per_row[n]
//
// R4: single fused GEMM. BN=64 env x BM=256 m (full support) -> A read once.
// A fp32 from HBM via VGPR (depth-2 register prefetch), convert+||ps||^2 fused
// in staging. B pre-converted bf16 (2 MB, L2-resident). LDS ping-pong, one
// barrier/iter, no global_load_lds (avoids vmcnt(0) drain at barriers).
// Fragment-major LDS layout: frag ds_read_b128 conflict-free.

constexpr int kNEnv     = 100000;
constexpr int kDPS      = 512;
constexpr int kNSpecies = 4;
constexpr int kNSupport = 256;
constexpr int kCap      = 32768;

constexpr int BN    = 64;           // envs per block
constexpr int BK    = 32;           // k per iter
constexpr int KITER = kDPS / BK;    // 16

typedef __attribute__((ext_vector_type(8))) short short8;
typedef __attribute__((ext_vector_type(4))) float f32x4;

__device__ __forceinline__ short8 pack_bf16x8(const float4& a, const float4& b) {
  union { short8 v; __hip_bfloat162 h[4]; } u;
  u.h[0] = __float22bfloat162_rn({a.x, a.y});
  u.h[1] = __float22bfloat162_rn({a.z, a.w});
  u.h[2] = __float22bfloat162_rn({b.x, b.y});
  u.h[3] = __float22bfloat162_rn({b.z, b.w});
  return u.v;
}

// ---------------- single-pass species bucket scatter ----------------
__global__ void scatter_kernel(const int* __restrict__ species, const int* __restrict__ sid,
                               int* __restrict__ cnt, int* __restrict__ perm,
                               int* __restrict__ sidp) {
  __shared__ int lcnt[kNSpecies];
  __shared__ int lbase[kNSpecies];
  int t = threadIdx.x;
  if (t < kNSpecies) lcnt[t] = 0;
  __syncthreads();
  int i = blockIdx.x * 256 + t;
  bool v = i < kNEnv;
  int s = 0, r = 0, g = 0;
  if (v) { s = species[i]; r = atomicAdd(&lcnt[s], 1); g = sid[i]; }
  __syncthreads();
  if (t < kNSpecies) lbase[t] = lcnt[t] ? atomicAdd(&cnt[t], lcnt[t]) : 0;
  __syncthreads();
  if (v) {
    int d = s * kCap + lbase[s] + r;
    perm[d] = i;
    sidp[d] = g;
  }
}

// ---------------- sp fp32 -> bf16 (2 MB, ~3 us) ----------------
__global__ __launch_bounds__(256) void convert_sp_kernel(
    const float* __restrict__ sp, short* __restrict__ sp_bf) {
  size_t g = ((size_t)blockIdx.x * 256 + threadIdx.x) * 8;
  float4 x = *(const float4*)(sp + g);
  float4 y = *(const float4*)(sp + g + 4);
  *(short8*)(sp_bf + g) = pack_bf16x8(x, y);
}

// ---------------- fused GEMM + norm + square-weight reduce + segsum ----------
// 256 threads = 4 waves. Wave wv: 64 env x 64 m (m quarter wv).
// Staging coords: thread t -> row r=t>>2, k-chunk c=t&3 (8 elements).
// LDS fragment-major: [chunk c][row][8 shorts] -> frag reads fully coalesced.
__global__ __launch_bounds__(256, 3) void gap_gemm_kernel(
    const float* __restrict__ ps, const short* __restrict__ sp_bf,
    const float* __restrict__ w, const int* __restrict__ cnt,
    const int* __restrict__ perm, const int* __restrict__ sidp,
    float* __restrict__ energy) {
  const int s     = blockIdx.y;
  const int count = min(cnt[s], kCap);
  const int tile0 = blockIdx.x * BN;
  if (tile0 >= count) return;

  __shared__ short a_fr[2][4 * BN * 8];        // 8 KB
  __shared__ short b_fr[2][4 * kNSupport * 8]; // 32 KB
  __shared__ float red[4][BN];
  __shared__ float sqs[4][BN];
  __shared__ int   prm[BN];

  const int tid  = threadIdx.x;
  const int wv   = tid >> 6;
  const int lane = tid & 63;
  const int l15  = lane & 15;
  const int lq   = lane >> 4;

  if (tid < BN) {
    int ge = tile0 + tid;
    prm[tid] = perm[s * kCap + (ge < count ? ge : count - 1)];
  }
  __syncthreads();

  const int c = tid & 3;   // k-chunk (8 elems)
  const int r = tid >> 2;  // row 0..63

  const float* aptr = ps + (size_t)prm[r] * kDPS + c * 8;
  const short* bbase = sp_bf + (size_t)s * kNSupport * kDPS + c * 8;
  const short* bptr0 = bbase + (size_t)(r +   0) * kDPS;
  const short* bptr1 = bbase + (size_t)(r +  64) * kDPS;
  const short* bptr2 = bbase + (size_t)(r + 128) * kDPS;
  const short* bptr3 = bbase + (size_t)(r + 192) * kDPS;

  f32x4 acc[4][4];
  #pragma unroll
  for (int i = 0; i < 4; ++i)
    #pragma unroll
    for (int j = 0; j < 4; ++j) acc[i][j] = (f32x4)0.f;

  float sq = 0.f;

  // prologue: A depth-2, B depth-1
  float4 apre[2][2];
  uint4  bpre[4];
  apre[0][0] = *(const float4*)(aptr + 0);
  apre[0][1] = *(const float4*)(aptr + 4);
  apre[1][0] = *(const float4*)(aptr + BK + 0);
  apre[1][1] = *(const float4*)(aptr + BK + 4);
  bpre[0] = *(const uint4*)(bptr0);
  bpre[1] = *(const uint4*)(bptr1);
  bpre[2] = *(const uint4*)(bptr2);
  bpre[3] = *(const uint4*)(bptr3);

  #pragma unroll 2
  for (int i = 0; i < KITER; ++i) {
    const int buf = i & 1;
    // consume prefetched A: norm + convert + stage
    float4 x = apre[buf][0], y = apre[buf][1];
    sq += x.x * x.x + x.y * x.y + x.z * x.z + x.w * x.w
        + y.x * y.x + y.y * y.y + y.z * y.z + y.w * y.w;
    *(short8*)&a_fr[buf][(c * BN + r) * 8] = pack_bf16x8(x, y);
    // consume prefetched B: stage
    *(uint4*)&b_fr[buf][(c * kNSupport + r +   0) * 8] = bpre[0];
    *(uint4*)&b_fr[buf][(c * kNSupport + r +  64) * 8] = bpre[1];
    *(uint4*)&b_fr[buf][(c * kNSupport + r + 128) * 8] = bpre[2];
    *(uint4*)&b_fr[buf][(c * kNSupport + r + 192) * 8] = bpre[3];
    // issue next loads (stay in flight across the barrier)
    if (i + 2 < KITER) {
      int k2 = (i + 2) * BK;
      apre[buf][0] = *(const float4*)(aptr + k2 + 0);
      apre[buf][1] = *(const float4*)(aptr + k2 + 4);
    }
    if (i + 1 < KITER) {
      int k1 = (i + 1) * BK;
      bpre[0] = *(const uint4*)(bptr0 + k1);
      bpre[1] = *(const uint4*)(bptr1 + k1);
      bpre[2] = *(const uint4*)(bptr2 + k1);
      bpre[3] = *(const uint4*)(bptr3 + k1);
    }
    __syncthreads();
    // fragments (conflict-free b128) + 16 MFMA
    short8 af[4], bf4[4];
    #pragma unroll
    for (int f = 0; f < 4; ++f)
      af[f] = *(const short8*)&a_fr[buf][(lq * BN + f * 16 + l15) * 8];
    #pragma unroll
    for (int f = 0; f < 4; ++f)
      bf4[f] = *(const short8*)&b_fr[buf][(lq * kNSupport + wv * 64 + f * 16 + l15) * 8];
    #pragma unroll
    for (int fi = 0; fi < 4; ++fi)
      #pragma unroll
      for (int fj = 0; fj < 4; ++fj)
        acc[fi][fj] = __builtin_amdgcn_mfma_f32_16x16x32_bf16(af[fi], bf4[fj], acc[fi][fj], 0, 0, 0);
  }

  sqs[c][r] = sq;

  // epilogue: contrib = sum_m w_m * C^2 ; C/D: col(m)=l15, row(env)=lq*4+reg
  const float* w_s = w + s * kNSupport;
  float wgt[4];
  #pragma unroll
  for (int fj = 0; fj < 4; ++fj) wgt[fj] = w_s[wv * 64 + fj * 16 + l15];

  #pragma unroll
  for (int fi = 0; fi < 4; ++fi) {
    #pragma unroll
    for (int rr = 0; rr < 4; ++rr) {
      float p = 0.f;
      #pragma unroll
      for (int fj = 0; fj < 4; ++fj) {
        float cv = acc[fi][fj][rr];
        p += cv * cv * wgt[fj];
      }
      p += __shfl_xor(p, 1, 64);
      p += __shfl_xor(p, 2, 64);
      p += __shfl_xor(p, 4, 64);
      p += __shfl_xor(p, 8, 64);
      if (l15 == 0) red[wv][fi * 16 + lq * 4 + rr] = p;
    }
  }
  __syncthreads();
  if (tid < BN) {
    float v = red[0][tid] + red[1][tid] + red[2][tid] + red[3][tid];
    float inv = 1.0f / (sqs[0][tid] + sqs[1][tid] + sqs[2][tid] + sqs[3][tid]);
    int g = tile0 + tid;
    if (g < count)
      atomicAdd(&energy[sidp[s * kCap + g]], v * inv);
  }
}

extern "C" void kernel_launch(void* const* d_in, const int* in_sizes, int n_in,
                              void* d_out, int out_size, void* d_ws, size_t ws_size,
                              hipStream_t stream) {
  const float* ps      = (const float*)d_in[0];
  const float* sp      = (const float*)d_in[1];
  const float* w       = (const float*)d_in[2];
  const int*   species = (const int*)d_in[3];
  const int*   sid     = (const int*)d_in[4];
  float* energy = (float*)d_out;

  char* wsb = (char*)d_ws;
  size_t off = 0;
  int* cnt  = (int*)(wsb + off); off += 256;
  int* perm = (int*)(wsb + off); off += (size_t)kNSpecies * kCap * 4;
  int* sidp = (int*)(wsb + off); off += (size_t)kNSpecies * kCap * 4;
  short* sp_bf = (short*)(wsb + off);

  hipMemsetAsync(cnt, 0, 16, stream);
  hipMemsetAsync(energy, 0, out_size * sizeof(float), stream);

  scatter_kernel<<<(kNEnv + 255) / 256, 256, 0, stream>>>(species, sid, cnt, perm, sidp);
  convert_sp_kernel<<<(kNSpecies * kNSupport * kDPS) / (256 * 8), 256, 0, stream>>>(sp, sp_bf);

  dim3 grid(kCap / BN, kNSpecies);  // (512, 4); early-out past count
  gap_gemm_kernel<<<grid, 256, 0, stream>>>(ps, sp_bf, w, cnt, perm, sidp, energy);
}